// Round 19
// baseline (262.189 us; speedup 1.0000x reference)
//
#include <hip/hip_runtime.h>

typedef __attribute__((ext_vector_type(8))) short bf16x8;
typedef __attribute__((ext_vector_type(4))) short s16x4;
typedef __attribute__((ext_vector_type(4))) float f32x4;

#define MFMA16 __builtin_amdgcn_mfma_f32_16x16x32_bf16

#if __has_builtin(__builtin_amdgcn_exp2f)
__device__ __forceinline__ float exp2_raw(float x) { return __builtin_amdgcn_exp2f(x); }
#else
__device__ __forceinline__ float exp2_raw(float x) {
    float r;
    asm volatile("v_exp_f32 %0, %1" : "=v"(r) : "v"(x));
    return r;
}
#endif

__device__ __forceinline__ short bf16s(float f) {
    __bf16 h = (__bf16)f;                 // RNE, lowers to v_cvt_pk_bf16_f32 pairs
    return __builtin_bit_cast(short, h);
}

__device__ __forceinline__ void gload16(const char* g, char* l) {
    __builtin_amdgcn_global_load_lds(
        (const __attribute__((address_space(1))) unsigned int*)g,
        (__attribute__((address_space(3))) unsigned int*)l, 16, 0, 0);
}

// ===== fused prepass: K,V fp32 -> pre-swizzled bf16 8KB tile-images =====
// blocks 0..1023: K image.  blocks 1024..2047: V image (transposed).
__global__ __launch_bounds__(256) void prep_kv(const float* __restrict__ K,
                                               const float* __restrict__ V,
                                               char* __restrict__ Kimg,
                                               char* __restrict__ Vimg) {
    const int t = threadIdx.x;
    if (blockIdx.x < 1024) {
        const int bid = blockIdx.x;        // head*64 + it
        const int c = t & 3, r = t >> 2;
        char* dst = Kimg + (size_t)bid * 8192;
        const float* src = K + (size_t)bid * 4096 + (size_t)r * 64 + c * 16;
        float e[16];
        *(float4*)(e)      = *(const float4*)(src);
        *(float4*)(e + 4)  = *(const float4*)(src + 4);
        *(float4*)(e + 8)  = *(const float4*)(src + 8);
        *(float4*)(e + 12) = *(const float4*)(src + 12);
#pragma unroll
        for (int lg = 0; lg < 4; ++lg) {
            s16x4 wv;
#pragma unroll
            for (int j = 0; j < 4; ++j) wv[j] = bf16s(e[lg * 4 + j]);
            const unsigned f = (unsigned)((((c >> 1) * 4 + lg) ^ (r & 7)));
            *(s16x4*)(dst + r * 128 + f * 16 + (c & 1) * 8) = wv;
        }
    } else {
        const int bid = blockIdx.x - 1024; // head*64 + it
        const int head = bid >> 6, it = bid & 63;
        const int b = head >> 3, h = head & 7;
        const int d = t & 63, f0 = t >> 6;
        char* dst = Vimg + (size_t)bid * 8192;
#pragma unroll
        for (int ff = 0; ff < 2; ++ff) {
            const int f = f0 + ff * 4;
            const int hh = f >> 2, lg = f & 3;
            const int kv0 = hh * 32 + lg * 4;
            const float* src = V + ((size_t)b * 4096 + it * 64 + kv0) * 512 + h * 64 + d;
            bf16x8 wv;
#pragma unroll
            for (int j = 0; j < 4; ++j) wv[j]     = bf16s(src[(size_t)j * 512]);
#pragma unroll
            for (int j = 0; j < 4; ++j) wv[4 + j] = bf16s(src[(size_t)(16 + j) * 512]);
            *(bf16x8*)(dst + d * 128 + (unsigned)((f ^ (d & 7)) * 16)) = wv;
        }
    }
}

// ===== main: 4 INDEPENDENT free-running waves per block, in-block merge =====
// 1024 blocks x 256 threads. Block = one (head, 64-q tile); wave w = kv quarter w
// (16 iters of 64-kv image tiles). NO __syncthreads in the loop -- each wave owns
// a private 8.25KB LDS quadrant and free-runs (R14-18 structure), but packaging
// 4 waves/workgroup defeats the 2-waves/EU scheduling cap observed with 1-wave
// blocks (R14-18 all ~18% occupancy; R6 (256,4)->40% proves the knob).
// launch_bounds(256,3): VGPR budget ~168 >> 104 live set (no R5/R6 spill), while
// allowing 12-16 waves/CU. Per wave-iter (single 8KB buffer, alternating K/V):
//   vmcnt(0) -> read K frags -> lgkmcnt(0) -> stage V(it)   -> QK ~ exp2(st0)
//   vmcnt(0) -> read V frags -> lgkmcnt(0) -> stage K(it+1) -> PV ~ exp2(st1)
// Rowsums on the MFMA pipe (ones B-operand). No max tracking: p = exp2(s).
// Epilogue: ONE barrier; waves 1-3 park bf16 partials + rowsums in their LDS
// quadrant; wave 0 merges, normalizes, stores fp32. No merge kernel.
__global__ __launch_bounds__(256, 3)
void sdpa_fa_kernel(const float* __restrict__ Q, const char* __restrict__ Kimg,
                    const char* __restrict__ Vimg, float* __restrict__ Out) {
    __shared__ __align__(16) char LDS[33792];   // 4 x (8192 stage/merge + 256 ls)

    const int bid  = blockIdx.x;
    const int xcd  = bid & 7;
    const int idx  = bid >> 3;               // 0..127
    const int head = xcd + 8 * (idx >> 6);   // 2 heads/XCD -> images L2-resident
    const int qt   = idx & 63;               // 64-row q tile

    const int t   = threadIdx.x;
    const int w   = t >> 6;                  // wave = kv quarter 0..3
    const int l   = t & 63;
    const int lg  = l >> 4;
    const int lc  = l & 15;
    const int lc7 = lc & 7;

    const int hb = head * 64 + w * 16;       // this wave's 16 image tiles
    char* LB = LDS + w * 8448;               // private stage buffer
    float* LSw = (float*)(LB + 8192);        // private rowsum parking (64 f32)

    const float C1 = (float)(1.4426950408889634 / 22.627416997969522); // log2(e)/sqrt(512)

    // ---- Q fragments qf[qi][half] (64 q rows, same for all 4 waves) ----
    bf16x8 qf[4][2];
#pragma unroll
    for (int qi = 0; qi < 4; ++qi) {
        const int qrow = qt * 64 + qi * 16 + lc;
        const float* qp = Q + ((size_t)head * 4096 + qrow) * 64;
#pragma unroll
        for (int half = 0; half < 2; ++half) {
            bf16x8 f;
#pragma unroll
            for (int j = 0; j < 4; ++j) {
                f[j]     = bf16s(qp[half * 32 + lg * 4 + j] * C1);
                f[4 + j] = bf16s(qp[half * 32 + 16 + lg * 4 + j] * C1);
            }
            qf[qi][half] = f;
        }
    }

    bf16x8 ones;
#pragma unroll
    for (int j = 0; j < 8; ++j) ones[j] = (short)0x3F80;   // bf16 1.0

    f32x4 Oa[4][4];
    f32x4 ls[4];
#pragma unroll
    for (int qi = 0; qi < 4; ++qi) {
        ls[qi] = (f32x4){0.f, 0.f, 0.f, 0.f};
#pragma unroll
        for (int dt = 0; dt < 4; ++dt) Oa[qi][dt] = (f32x4){0.f, 0.f, 0.f, 0.f};
    }

    // ---- hoisted LDS read offsets (loop-invariant; K and V share the buffer) ----
    unsigned off0[4], off1[4];
#pragma unroll
    for (int g = 0; g < 4; ++g) {
        off0[g] = (unsigned)((g * 16 + lc) * 128 + (((0 + lg) ^ lc7) * 16));
        off1[g] = (unsigned)((g * 16 + lc) * 128 + (((4 + lg) ^ lc7) * 16));
    }

    auto stage_k = [&](int it) {
        const char* gk = Kimg + (size_t)(hb + it) * 8192 + l * 16;
#pragma unroll
        for (int i = 0; i < 8; ++i) gload16(gk + i * 1024, LB + i * 1024);
    };
    auto stage_v = [&](int it) {
        const char* gv = Vimg + (size_t)(hb + it) * 8192 + l * 16;
#pragma unroll
        for (int i = 0; i < 8; ++i) gload16(gv + i * 1024, LB + i * 1024);
    };

    stage_k(0);

#pragma unroll 1
    for (int it = 0; it < 16; ++it) {
        // ---- K phase ----
        asm volatile("s_waitcnt vmcnt(0)" ::: "memory");
        __builtin_amdgcn_sched_barrier(0);
        bf16x8 kf[4][2];
#pragma unroll
        for (int g = 0; g < 4; ++g) {
            kf[g][0] = *(const bf16x8*)(LB + off0[g]);
            kf[g][1] = *(const bf16x8*)(LB + off1[g]);
        }
        asm volatile("s_waitcnt lgkmcnt(0)" ::: "memory");  // K region dead
        __builtin_amdgcn_sched_barrier(0);
        stage_v(it);                    // V loads fly under QK compute
        __builtin_amdgcn_sched_barrier(0);

        // ---- QK h0 (16 MFMA), then QK h1 interleaved with exp2(st0) ----
        f32x4 st0[4][2], st1[4][2];
        __builtin_amdgcn_s_setprio(1);
#pragma unroll
        for (int g2 = 0; g2 < 2; ++g2)
#pragma unroll
            for (int qi = 0; qi < 4; ++qi) {
                f32x4 a = (f32x4){0.f, 0.f, 0.f, 0.f};
                a = MFMA16(kf[g2][0], qf[qi][0], a, 0, 0, 0);
                a = MFMA16(kf[g2][1], qf[qi][1], a, 0, 0, 0);
                st0[qi][g2] = a;
            }
#pragma unroll
        for (int g2 = 0; g2 < 2; ++g2)
#pragma unroll
            for (int qi = 0; qi < 4; ++qi) {
                f32x4 a = (f32x4){0.f, 0.f, 0.f, 0.f};
                a = MFMA16(kf[g2 + 2][0], qf[qi][0], a, 0, 0, 0);
                a = MFMA16(kf[g2 + 2][1], qf[qi][1], a, 0, 0, 0);
                st1[qi][g2] = a;
#pragma unroll
                for (int r = 0; r < 4; ++r) st0[qi][g2][r] = exp2_raw(st0[qi][g2][r]);
            }
        __builtin_amdgcn_s_setprio(0);

        bf16x8 pfr0[4];
#pragma unroll
        for (int qi = 0; qi < 4; ++qi) {
            bf16x8 f;
#pragma unroll
            for (int j = 0; j < 4; ++j) {
                f[j]     = bf16s(st0[qi][0][j]);
                f[4 + j] = bf16s(st0[qi][1][j]);
            }
            pfr0[qi] = f;
        }

        // ---- V phase ----
        asm volatile("s_waitcnt vmcnt(0)" ::: "memory");
        __builtin_amdgcn_sched_barrier(0);
        bf16x8 vf[4][2];
#pragma unroll
        for (int dt = 0; dt < 4; ++dt) {
            vf[dt][0] = *(const bf16x8*)(LB + off0[dt]);
            vf[dt][1] = *(const bf16x8*)(LB + off1[dt]);
        }
        asm volatile("s_waitcnt lgkmcnt(0)" ::: "memory");  // V region dead
        __builtin_amdgcn_sched_barrier(0);
        if (it + 1 < 16) stage_k(it + 1);   // K(next) flies under PV compute
        __builtin_amdgcn_sched_barrier(0);

        // ---- PV h0 + rowsum0 interleaved with exp2(st1) ----
        __builtin_amdgcn_s_setprio(1);
#pragma unroll
        for (int qi = 0; qi < 4; ++qi) {
            ls[qi] = MFMA16(pfr0[qi], ones, ls[qi], 0, 0, 0);
#pragma unroll
            for (int r = 0; r < 4; ++r) st1[qi][0][r] = exp2_raw(st1[qi][0][r]);
            Oa[qi][0] = MFMA16(pfr0[qi], vf[0][0], Oa[qi][0], 0, 0, 0);
            Oa[qi][1] = MFMA16(pfr0[qi], vf[1][0], Oa[qi][1], 0, 0, 0);
#pragma unroll
            for (int r = 0; r < 4; ++r) st1[qi][1][r] = exp2_raw(st1[qi][1][r]);
            Oa[qi][2] = MFMA16(pfr0[qi], vf[2][0], Oa[qi][2], 0, 0, 0);
            Oa[qi][3] = MFMA16(pfr0[qi], vf[3][0], Oa[qi][3], 0, 0, 0);
        }
        __builtin_amdgcn_s_setprio(0);

        bf16x8 pfr1[4];
#pragma unroll
        for (int qi = 0; qi < 4; ++qi) {
            bf16x8 f;
#pragma unroll
            for (int j = 0; j < 4; ++j) {
                f[j]     = bf16s(st1[qi][0][j]);
                f[4 + j] = bf16s(st1[qi][1][j]);
            }
            pfr1[qi] = f;
        }

        // ---- PV h1 + rowsum1: 20 MFMA ----
        __builtin_amdgcn_s_setprio(1);
#pragma unroll
        for (int qi = 0; qi < 4; ++qi) {
            ls[qi] = MFMA16(pfr1[qi], ones, ls[qi], 0, 0, 0);
#pragma unroll
            for (int dt = 0; dt < 4; ++dt)
                Oa[qi][dt] = MFMA16(pfr1[qi], vf[dt][1], Oa[qi][dt], 0, 0, 0);
        }
        __builtin_amdgcn_s_setprio(0);
    }

    // ---- epilogue: in-block merge (one barrier, after the loop) ----
    if (w != 0) {
        unsigned short* Ob = (unsigned short*)LB;   // [64 q][64 d] bf16 partial
#pragma unroll
        for (int qi = 0; qi < 4; ++qi)
#pragma unroll
            for (int r = 0; r < 4; ++r) {
                const int q = qi * 16 + lg * 4 + r;
#pragma unroll
                for (int dt = 0; dt < 4; ++dt)
                    Ob[q * 64 + dt * 16 + lc] = (unsigned short)bf16s(Oa[qi][dt][r]);
                if (lc == 0) LSw[q] = ls[qi][r];
            }
    }
    __syncthreads();
    if (w == 0) {
#pragma unroll
        for (int qi = 0; qi < 4; ++qi)
#pragma unroll
            for (int r = 0; r < 4; ++r) {
                const int q = qi * 16 + lg * 4 + r;
                float tot = ls[qi][r];
#pragma unroll
                for (int wv = 1; wv < 4; ++wv)
                    tot += *(const float*)(LDS + wv * 8448 + 8192 + q * 4);
                const float inv = 1.0f / tot;
                float* og = Out + ((size_t)head * 4096 + qt * 64 + q) * 64 + lc;
#pragma unroll
                for (int dt = 0; dt < 4; ++dt) {
                    float s = Oa[qi][dt][r];
#pragma unroll
                    for (int wv = 1; wv < 4; ++wv) {
                        const unsigned short u = *(const unsigned short*)
                            (LDS + wv * 8448 + (q * 64 + dt * 16 + lc) * 2);
                        s += __builtin_bit_cast(float, (unsigned)u << 16);
                    }
                    og[dt * 16] = s * inv;
                }
            }
    }
}

extern "C" void kernel_launch(void* const* d_in, const int* in_sizes, int n_in,
                              void* d_out, int out_size, void* d_ws, size_t ws_size,
                              hipStream_t stream) {
    const float* Q = (const float*)d_in[0];
    const float* K = (const float*)d_in[1];
    const float* V = (const float*)d_in[2];
    float* Out = (float*)d_out;
    char* Kimg = (char*)d_ws;                      // 8 MB
    char* Vimg = (char*)d_ws + (size_t)8388608;    // 8 MB
    prep_kv<<<dim3(2048), dim3(256), 0, stream>>>(K, V, Kimg, Vimg);
    sdpa_fa_kernel<<<dim3(1024), dim3(256), 0, stream>>>(Q, Kimg, Vimg, Out);
}

// Round 20
// 90.966 us; speedup vs baseline: 2.8823x; 2.8823x over previous
//
#include <hip/hip_runtime.h>

typedef __attribute__((ext_vector_type(8))) short bf16x8;
typedef __attribute__((ext_vector_type(4))) short s16x4;
typedef __attribute__((ext_vector_type(4))) float f32x4;

#define MFMA16 __builtin_amdgcn_mfma_f32_16x16x32_bf16

#if __has_builtin(__builtin_amdgcn_exp2f)
__device__ __forceinline__ float exp2_raw(float x) { return __builtin_amdgcn_exp2f(x); }
#else
__device__ __forceinline__ float exp2_raw(float x) {
    float r;
    asm volatile("v_exp_f32 %0, %1" : "=v"(r) : "v"(x));
    return r;
}
#endif

__device__ __forceinline__ short bf16s(float f) {
    __bf16 h = (__bf16)f;                 // RNE, lowers to v_cvt_pk_bf16_f32 pairs
    return __builtin_bit_cast(short, h);
}

__device__ __forceinline__ void gload16(const char* g, char* l) {
    __builtin_amdgcn_global_load_lds(
        (const __attribute__((address_space(1))) unsigned int*)g,
        (__attribute__((address_space(3))) unsigned int*)l, 16, 0, 0);
}

// ===== fused prepass: K,V fp32 -> pre-swizzled bf16 8KB tile-images =====
// blocks 0..1023: K image.  blocks 1024..2047: V image (transposed).
__global__ __launch_bounds__(256) void prep_kv(const float* __restrict__ K,
                                               const float* __restrict__ V,
                                               char* __restrict__ Kimg,
                                               char* __restrict__ Vimg) {
    const int t = threadIdx.x;
    if (blockIdx.x < 1024) {
        const int bid = blockIdx.x;        // head*64 + it
        const int c = t & 3, r = t >> 2;
        char* dst = Kimg + (size_t)bid * 8192;
        const float* src = K + (size_t)bid * 4096 + (size_t)r * 64 + c * 16;
        float e[16];
        *(float4*)(e)      = *(const float4*)(src);
        *(float4*)(e + 4)  = *(const float4*)(src + 4);
        *(float4*)(e + 8)  = *(const float4*)(src + 8);
        *(float4*)(e + 12) = *(const float4*)(src + 12);
#pragma unroll
        for (int lg = 0; lg < 4; ++lg) {
            s16x4 wv;
#pragma unroll
            for (int j = 0; j < 4; ++j) wv[j] = bf16s(e[lg * 4 + j]);
            const unsigned f = (unsigned)((((c >> 1) * 4 + lg) ^ (r & 7)));
            *(s16x4*)(dst + r * 128 + f * 16 + (c & 1) * 8) = wv;
        }
    } else {
        const int bid = blockIdx.x - 1024; // head*64 + it
        const int head = bid >> 6, it = bid & 63;
        const int b = head >> 3, h = head & 7;
        const int d = t & 63, f0 = t >> 6;
        char* dst = Vimg + (size_t)bid * 8192;
#pragma unroll
        for (int ff = 0; ff < 2; ++ff) {
            const int f = f0 + ff * 4;
            const int hh = f >> 2, lg = f & 3;
            const int kv0 = hh * 32 + lg * 4;
            const float* src = V + ((size_t)b * 4096 + it * 64 + kv0) * 512 + h * 64 + d;
            bf16x8 wv;
#pragma unroll
            for (int j = 0; j < 4; ++j) wv[j]     = bf16s(src[(size_t)j * 512]);
#pragma unroll
            for (int j = 0; j < 4; ++j) wv[4 + j] = bf16s(src[(size_t)(16 + j) * 512]);
            *(bf16x8*)(dst + d * 128 + (unsigned)((f ^ (d & 7)) * 16)) = wv;
        }
    }
}

// ===== main: 4 free-running waves/block, (256,2) spill-safe, in-block merge =====
// 1024 blocks x 256 threads. Block = (head, 64-q tile); wave w = kv quarter
// (16 iters of 64-kv tiles). NO __syncthreads in the loop; each wave owns a
// private 16.6KB LDS region and runs R17's counted-vmcnt pipeline:
//   vmcnt(8) -> read K frags -> lgkmcnt(0) -> stage K(next) -> QK ~ exp2
//   vmcnt(8) -> read V frags -> lgkmcnt(0) -> stage V(next) -> PV ~ exp2
// launch_bounds(256,2): VGPR budget 128 >= 104 live set (R19's (256,3)->84
// proved any min>=3 spills ~1GB on this stack). ANTI-PHASE STAGGER: odd-idx
// blocks s_sleep ~320cyc before the loop, tipping SIMD-partner waves into the
// self-stabilizing anti-phase state (m114: hetero-phase waves co-schedule
// time~max, not sum; our 90% MfmaUtil+VALUBusy sum-wall is the locked state).
// Rowsums on the MFMA pipe (ones B-operand). No max tracking: p = exp2(s).
// Epilogue: vmcnt(0), waves 1-3 park bf16 partials in their LDS region, one
// barrier, wave 0 merges + normalizes + stores. No merge kernel.
__global__ __launch_bounds__(256, 2)
void sdpa_fa_kernel(const float* __restrict__ Q, const char* __restrict__ Kimg,
                    const char* __restrict__ Vimg, float* __restrict__ Out) {
    __shared__ __align__(16) char LDS[66560];   // 4 x (8K Kstage | 8K Vstage | 256B ls)

    const int bid  = blockIdx.x;
    const int xcd  = bid & 7;
    const int idx  = bid >> 3;               // 0..127
    const int head = xcd + 8 * (idx >> 6);   // 2 heads/XCD -> images L2-resident
    const int qt   = idx & 63;               // 64-row q tile

    const int t   = threadIdx.x;
    const int w   = t >> 6;                  // wave = kv quarter 0..3
    const int l   = t & 63;
    const int lg  = l >> 4;
    const int lc  = l & 15;
    const int lc7 = lc & 7;

    const int hb = head * 64 + w * 16;       // this wave's 16 image tiles
    char* LB = LDS + w * 16640;              // private region

    const float C1 = (float)(1.4426950408889634 / 22.627416997969522); // log2(e)/sqrt(512)

    // ---- Q fragments qf[qi][half] (64 q rows, shared q-tile), resident ----
    bf16x8 qf[4][2];
#pragma unroll
    for (int qi = 0; qi < 4; ++qi) {
        const int qrow = qt * 64 + qi * 16 + lc;
        const float* qp = Q + ((size_t)head * 4096 + qrow) * 64;
#pragma unroll
        for (int half = 0; half < 2; ++half) {
            bf16x8 f;
#pragma unroll
            for (int j = 0; j < 4; ++j) {
                f[j]     = bf16s(qp[half * 32 + lg * 4 + j] * C1);
                f[4 + j] = bf16s(qp[half * 32 + 16 + lg * 4 + j] * C1);
            }
            qf[qi][half] = f;
        }
    }

    bf16x8 ones;
#pragma unroll
    for (int j = 0; j < 8; ++j) ones[j] = (short)0x3F80;   // bf16 1.0

    f32x4 Oa[4][4];
    f32x4 ls[4];
#pragma unroll
    for (int qi = 0; qi < 4; ++qi) {
        ls[qi] = (f32x4){0.f, 0.f, 0.f, 0.f};
#pragma unroll
        for (int dt = 0; dt < 4; ++dt) Oa[qi][dt] = (f32x4){0.f, 0.f, 0.f, 0.f};
    }

    // ---- hoisted LDS read offsets ----
    unsigned off0[4], off1[4];
#pragma unroll
    for (int g = 0; g < 4; ++g) {
        off0[g] = (unsigned)((g * 16 + lc) * 128 + (((0 + lg) ^ lc7) * 16));
        off1[g] = (unsigned)((g * 16 + lc) * 128 + (((4 + lg) ^ lc7) * 16));
    }

    auto stage_k = [&](int it) {
        const char* gk = Kimg + (size_t)(hb + it) * 8192 + l * 16;
#pragma unroll
        for (int i = 0; i < 8; ++i) gload16(gk + i * 1024, LB + i * 1024);
    };
    auto stage_v = [&](int it) {
        const char* gv = Vimg + (size_t)(hb + it) * 8192 + l * 16;
#pragma unroll
        for (int i = 0; i < 8; ++i) gload16(gv + i * 1024, LB + 8192 + i * 1024);
    };

    // ---- anti-phase stagger: odd blocks delay ~half an iteration ----
    if (idx & 1) __builtin_amdgcn_s_sleep(5);   // ~320 cyc

    stage_k(0);
    stage_v(0);

#pragma unroll 1
    for (int it = 0; it < 16; ++it) {
        const int nx = (it + 1) & 15;   // static wait pattern; last reload harmless

        // ---- K phase: wait the 8 K loads (V's 8 still in flight) ----
        asm volatile("s_waitcnt vmcnt(8)" ::: "memory");
        __builtin_amdgcn_sched_barrier(0);
        bf16x8 kf[4][2];
#pragma unroll
        for (int g = 0; g < 4; ++g) {
            kf[g][0] = *(const bf16x8*)(LB + off0[g]);
            kf[g][1] = *(const bf16x8*)(LB + off1[g]);
        }
        asm volatile("s_waitcnt lgkmcnt(0)" ::: "memory");  // K region dead
        __builtin_amdgcn_sched_barrier(0);
        stage_k(nx);                    // K(next) flies under QK compute
        __builtin_amdgcn_sched_barrier(0);

        // ---- QK h0 (16 MFMA), then QK h1 interleaved with exp2(st0) ----
        f32x4 st0[4][2], st1[4][2];
        __builtin_amdgcn_s_setprio(1);
#pragma unroll
        for (int g2 = 0; g2 < 2; ++g2)
#pragma unroll
            for (int qi = 0; qi < 4; ++qi) {
                f32x4 a = (f32x4){0.f, 0.f, 0.f, 0.f};
                a = MFMA16(kf[g2][0], qf[qi][0], a, 0, 0, 0);
                a = MFMA16(kf[g2][1], qf[qi][1], a, 0, 0, 0);
                st0[qi][g2] = a;
            }
#pragma unroll
        for (int g2 = 0; g2 < 2; ++g2)
#pragma unroll
            for (int qi = 0; qi < 4; ++qi) {
                f32x4 a = (f32x4){0.f, 0.f, 0.f, 0.f};
                a = MFMA16(kf[g2 + 2][0], qf[qi][0], a, 0, 0, 0);
                a = MFMA16(kf[g2 + 2][1], qf[qi][1], a, 0, 0, 0);
                st1[qi][g2] = a;
#pragma unroll
                for (int r = 0; r < 4; ++r) st0[qi][g2][r] = exp2_raw(st0[qi][g2][r]);
            }
        __builtin_amdgcn_s_setprio(0);

        bf16x8 pfr0[4];
#pragma unroll
        for (int qi = 0; qi < 4; ++qi) {
            bf16x8 f;
#pragma unroll
            for (int j = 0; j < 4; ++j) {
                f[j]     = bf16s(st0[qi][0][j]);
                f[4 + j] = bf16s(st0[qi][1][j]);
            }
            pfr0[qi] = f;
        }

        // ---- V phase: wait the 8 V loads (K(next) still in flight) ----
        asm volatile("s_waitcnt vmcnt(8)" ::: "memory");
        __builtin_amdgcn_sched_barrier(0);
        bf16x8 vf[4][2];
#pragma unroll
        for (int dt = 0; dt < 4; ++dt) {
            vf[dt][0] = *(const bf16x8*)(LB + 8192 + off0[dt]);
            vf[dt][1] = *(const bf16x8*)(LB + 8192 + off1[dt]);
        }
        asm volatile("s_waitcnt lgkmcnt(0)" ::: "memory");  // V region dead
        __builtin_amdgcn_sched_barrier(0);
        stage_v(nx);                    // V(next) flies under PV compute
        __builtin_amdgcn_sched_barrier(0);

        // ---- PV h0 + rowsum0 interleaved with exp2(st1) ----
        __builtin_amdgcn_s_setprio(1);
#pragma unroll
        for (int qi = 0; qi < 4; ++qi) {
            ls[qi] = MFMA16(pfr0[qi], ones, ls[qi], 0, 0, 0);
#pragma unroll
            for (int r = 0; r < 4; ++r) st1[qi][0][r] = exp2_raw(st1[qi][0][r]);
            Oa[qi][0] = MFMA16(pfr0[qi], vf[0][0], Oa[qi][0], 0, 0, 0);
            Oa[qi][1] = MFMA16(pfr0[qi], vf[1][0], Oa[qi][1], 0, 0, 0);
#pragma unroll
            for (int r = 0; r < 4; ++r) st1[qi][1][r] = exp2_raw(st1[qi][1][r]);
            Oa[qi][2] = MFMA16(pfr0[qi], vf[2][0], Oa[qi][2], 0, 0, 0);
            Oa[qi][3] = MFMA16(pfr0[qi], vf[3][0], Oa[qi][3], 0, 0, 0);
        }
        __builtin_amdgcn_s_setprio(0);

        bf16x8 pfr1[4];
#pragma unroll
        for (int qi = 0; qi < 4; ++qi) {
            bf16x8 f;
#pragma unroll
            for (int j = 0; j < 4; ++j) {
                f[j]     = bf16s(st1[qi][0][j]);
                f[4 + j] = bf16s(st1[qi][1][j]);
            }
            pfr1[qi] = f;
        }

        // ---- PV h1 + rowsum1: 20 MFMA ----
        __builtin_amdgcn_s_setprio(1);
#pragma unroll
        for (int qi = 0; qi < 4; ++qi) {
            ls[qi] = MFMA16(pfr1[qi], ones, ls[qi], 0, 0, 0);
#pragma unroll
            for (int dt = 0; dt < 4; ++dt)
                Oa[qi][dt] = MFMA16(pfr1[qi], vf[dt][1], Oa[qi][dt], 0, 0, 0);
        }
        __builtin_amdgcn_s_setprio(0);
    }

    // ---- epilogue: drain loads, in-block merge, normalize, store ----
    asm volatile("s_waitcnt vmcnt(0)" ::: "memory");   // outstanding stages -> LB
    __builtin_amdgcn_sched_barrier(0);
    if (w != 0) {
        unsigned short* Ob = (unsigned short*)LB;       // [64 q][64 d] bf16 partial
        float* LSp = (float*)(LB + 16384);
#pragma unroll
        for (int qi = 0; qi < 4; ++qi)
#pragma unroll
            for (int r = 0; r < 4; ++r) {
                const int q = qi * 16 + lg * 4 + r;
#pragma unroll
                for (int dt = 0; dt < 4; ++dt)
                    Ob[q * 64 + dt * 16 + lc] = (unsigned short)bf16s(Oa[qi][dt][r]);
                if (lc == 0) LSp[q] = ls[qi][r];
            }
    }
    __syncthreads();
    if (w == 0) {
#pragma unroll
        for (int qi = 0; qi < 4; ++qi)
#pragma unroll
            for (int r = 0; r < 4; ++r) {
                const int q = qi * 16 + lg * 4 + r;
                float tot = ls[qi][r];
#pragma unroll
                for (int wv = 1; wv < 4; ++wv)
                    tot += *(const float*)(LDS + wv * 16640 + 16384 + q * 4);
                const float inv = 1.0f / tot;
                float* og = Out + ((size_t)head * 4096 + qt * 64 + q) * 64 + lc;
#pragma unroll
                for (int dt = 0; dt < 4; ++dt) {
                    float s = Oa[qi][dt][r];
#pragma unroll
                    for (int wv = 1; wv < 4; ++wv) {
                        const unsigned short u = *(const unsigned short*)
                            (LDS + wv * 16640 + (q * 64 + dt * 16 + lc) * 2);
                        s += __builtin_bit_cast(float, (unsigned)u << 16);
                    }
                    og[dt * 16] = s * inv;
                }
            }
    }
}

extern "C" void kernel_launch(void* const* d_in, const int* in_sizes, int n_in,
                              void* d_out, int out_size, void* d_ws, size_t ws_size,
                              hipStream_t stream) {
    const float* Q = (const float*)d_in[0];
    const float* K = (const float*)d_in[1];
    const float* V = (const float*)d_in[2];
    float* Out = (float*)d_out;
    char* Kimg = (char*)d_ws;                      // 8 MB
    char* Vimg = (char*)d_ws + (size_t)8388608;    // 8 MB
    prep_kv<<<dim3(2048), dim3(256), 0, stream>>>(K, V, Kimg, Vimg);
    sdpa_fa_kernel<<<dim3(1024), dim3(256), 0, stream>>>(Q, Kimg, Vimg, Out);
}